// Round 1
// baseline (234.856 us; speedup 1.0000x reference)
//
#include <hip/hip_runtime.h>
#include <hip/hip_bf16.h>

#define Bn   16
#define LATn 512
#define Cn   512
#define Wn   4096
#define Fn   512

using bf16x8 = __attribute__((ext_vector_type(8))) short;
using f32x4  = __attribute__((ext_vector_type(4))) float;

__device__ __forceinline__ unsigned short f2bf(float x) {
    union { float f; unsigned int u; } v; v.f = x;
    unsigned int r = v.u + 0x7fffu + ((v.u >> 16) & 1u);
    return (unsigned short)(r >> 16);
}

// 1) affine[b][c] = latent[b,:] . affine_w[:,c] + affine_b[c]
__global__ void k_affine(const float* __restrict__ latent,
                         const float* __restrict__ aw,
                         const float* __restrict__ ab,
                         float* __restrict__ affine) {
    const int c = blockIdx.x * 256 + threadIdx.x;
    const int b = blockIdx.y;
    float s0 = 0.f, s1 = 0.f;
    for (int l = 0; l < LATn; l += 2) {
        s0 = fmaf(latent[b * LATn + l],     aw[(size_t)l * Cn + c],       s0);
        s1 = fmaf(latent[b * LATn + l + 1], aw[(size_t)(l + 1) * Cn + c], s1);
    }
    affine[b * Cn + c] = s0 + s1 + ab[c];
}

// 2) demod[b][f] = rsqrt(sum_{k,c} kw[k][c][f]^2 * affine[b][c]^2 + 1e-8)
__global__ void k_demod(const float* __restrict__ kw,
                        const float* __restrict__ affine,
                        float* __restrict__ demod) {
    const int f = blockIdx.x * 256 + threadIdx.x;
    const int b = blockIdx.y;
    float s0 = 0.f, s1 = 0.f, s2 = 0.f;
    for (int c = 0; c < Cn; ++c) {
        const float a  = affine[b * Cn + c];
        const float a2 = a * a;
        const float k0 = kw[((size_t)(0 * Cn + c)) * Fn + f];
        const float k1 = kw[((size_t)(1 * Cn + c)) * Fn + f];
        const float k2 = kw[((size_t)(2 * Cn + c)) * Fn + f];
        s0 = fmaf(k0 * k0, a2, s0);
        s1 = fmaf(k1 * k1, a2, s1);
        s2 = fmaf(k2 * k2, a2, s2);
    }
    demod[b * Fn + f] = rsqrtf(s0 + s1 + s2 + 1e-8f);
}

// 3) kt[k][f][c] = bf16(kw[k][c][f])   (K-contiguous A operand)
__global__ void k_tk(const float* __restrict__ kw, unsigned short* __restrict__ kt) {
    __shared__ float lds[32][65];
    const int t  = threadIdx.x;
    const int k  = blockIdx.z;
    const int c0 = blockIdx.x * 32;
    const int f0 = blockIdx.y * 64;
    #pragma unroll
    for (int i = 0; i < 8; ++i) {
        int e = t + 256 * i; int c = e >> 6; int f = e & 63;
        lds[c][f] = kw[((size_t)(k * Cn + c0 + c)) * Fn + f0 + f];
    }
    __syncthreads();
    #pragma unroll
    for (int i = 0; i < 8; ++i) {
        int e = t + 256 * i; int f = e >> 5; int c = e & 31;
        kt[((size_t)(k * Fn + f0 + f)) * Cn + c0 + c] = f2bf(lds[c][f]);
    }
}

// 4) xt[b][w][c] = bf16(content[b][c][w] * affine[b][c])  (K-contiguous B operand)
__global__ void k_tx(const float* __restrict__ content,
                     const float* __restrict__ affine,
                     unsigned short* __restrict__ xt) {
    __shared__ float lds[64][65];
    const int t  = threadIdx.x;
    const int b  = blockIdx.z;
    const int c0 = blockIdx.y * 64;
    const int w0 = blockIdx.x * 64;
    #pragma unroll
    for (int i = 0; i < 16; ++i) {
        int e = t + 256 * i; int c = e >> 6; int w = e & 63;
        lds[c][w] = content[((size_t)(b * Cn + c0 + c)) * Wn + w0 + w] * affine[b * Cn + c0 + c];
    }
    __syncthreads();
    #pragma unroll
    for (int i = 0; i < 16; ++i) {
        int e = t + 256 * i; int w = e >> 6; int c = e & 63;
        xt[((size_t)b * Wn + w0 + w) * Cn + c0 + c] = f2bf(lds[c][w]);
    }
}

// 5) main conv-GEMM: y[b][f][w] = leaky(demod[b][f] * sum_{k,c} kt[k][f][c]*xt[b][w+k-1][c] + kb[f])
#define BM 128
#define BN 128
#define BK 32
#define PADR 40   // padded LDS row length (elements); 80B rows -> ~2-way conflicts (free)

__global__ __launch_bounds__(256, 3)
void k_conv(const unsigned short* __restrict__ kt,
            const unsigned short* __restrict__ xt,
            const float* __restrict__ demod,
            const float* __restrict__ kb,
            float* __restrict__ y) {
    __shared__ unsigned short klds[3][BM][PADR];   // 30720 B
    __shared__ unsigned short xlds[BN + 2][PADR];  // 10400 B

    const int t  = threadIdx.x;
    const int w0 = blockIdx.x * BN;
    const int f0 = blockIdx.y * BM;
    const int b  = blockIdx.z;

    const int wave = t >> 6;
    const int lane = t & 63;
    const int wr   = wave >> 1;   // f-half of the 128x128 tile
    const int wc   = wave & 1;    // w-half
    const int l15  = lane & 15;
    const int lhi  = lane >> 4;   // 0..3

    f32x4 acc[4][4];
    #pragma unroll
    for (int m = 0; m < 4; ++m)
        #pragma unroll
        for (int n = 0; n < 4; ++n)
            #pragma unroll
            for (int r = 0; r < 4; ++r)
                acc[m][n][r] = 0.f;

    for (int cc = 0; cc < Cn / BK; ++cc) {
        const int c0 = cc * BK;
        // stage A: 3 k-planes, [128 f][32 c] each, 16B chunks
        #pragma unroll
        for (int k = 0; k < 3; ++k) {
            #pragma unroll
            for (int i = 0; i < 2; ++i) {
                const int q  = t + 256 * i;     // 0..511
                const int fr = q >> 2;          // 0..127
                const int c8 = (q & 3) * 8;
                const uint4 v = *(const uint4*)&kt[((size_t)(k * Fn + f0 + fr)) * Cn + c0 + c8];
                *(uint4*)&klds[k][fr][c8] = v;
            }
        }
        // stage X: [130 w][32 c] with halo, zero-padded at image edges
        for (int q = t; q < (BN + 2) * 4; q += 256) {
            const int wl = q >> 2;
            const int c8 = (q & 3) * 8;
            const int wg = w0 - 1 + wl;
            uint4 v = {0u, 0u, 0u, 0u};
            if ((unsigned)wg < (unsigned)Wn)
                v = *(const uint4*)&xt[((size_t)b * Wn + wg) * Cn + c0 + c8];
            *(uint4*)&xlds[wl][c8] = v;
        }
        __syncthreads();

        #pragma unroll
        for (int k = 0; k < 3; ++k) {
            bf16x8 af[4];
            #pragma unroll
            for (int m = 0; m < 4; ++m)
                af[m] = *(const bf16x8*)&klds[k][wr * 64 + m * 16 + l15][lhi * 8];
            #pragma unroll
            for (int n = 0; n < 4; ++n) {
                const bf16x8 bv = *(const bf16x8*)&xlds[wc * 64 + n * 16 + l15 + k][lhi * 8];
                #pragma unroll
                for (int m = 0; m < 4; ++m)
                    acc[m][n] = __builtin_amdgcn_mfma_f32_16x16x32_bf16(af[m], bv, acc[m][n], 0, 0, 0);
            }
        }
        __syncthreads();
    }

    // epilogue: demod * acc + kb, leaky_relu(0.2)
    #pragma unroll
    for (int m = 0; m < 4; ++m) {
        const int fb = f0 + wr * 64 + m * 16 + lhi * 4;   // base f for the 4 regs
        const float4 dmv = *(const float4*)&demod[b * Fn + fb];
        const float4 kbv = *(const float4*)&kb[fb];
        const float dmf[4] = {dmv.x, dmv.y, dmv.z, dmv.w};
        const float kbf[4] = {kbv.x, kbv.y, kbv.z, kbv.w};
        #pragma unroll
        for (int n = 0; n < 4; ++n) {
            const int w = w0 + wc * 64 + n * 16 + l15;
            #pragma unroll
            for (int r = 0; r < 4; ++r) {
                float v = fmaf(acc[m][n][r], dmf[r], kbf[r]);
                v = (v >= 0.f) ? v : 0.2f * v;
                y[((size_t)(b * Fn + fb + r)) * Wn + w] = v;
            }
        }
    }
}

extern "C" void kernel_launch(void* const* d_in, const int* in_sizes, int n_in,
                              void* d_out, int out_size, void* d_ws, size_t ws_size,
                              hipStream_t stream) {
    const float* latent  = (const float*)d_in[0];
    const float* content = (const float*)d_in[1];
    const float* aw      = (const float*)d_in[2];
    const float* ab      = (const float*)d_in[3];
    const float* kw      = (const float*)d_in[4];
    const float* kb      = (const float*)d_in[5];
    float* y = (float*)d_out;

    char* ws = (char*)d_ws;
    float*          affine = (float*)(ws);                       // 32 KB
    float*          demod  = (float*)(ws + 32768);               // 32 KB
    unsigned short* kt     = (unsigned short*)(ws + 65536);      // 1.5 MB
    unsigned short* xt     = (unsigned short*)(ws + 2u * 1024u * 1024u); // 64 MB
    if (ws_size < 2u * 1024u * 1024u + (size_t)Bn * Wn * Cn * 2u) return;  // need ~66 MB

    k_affine<<<dim3(Cn / 256, Bn),        256, 0, stream>>>(latent, aw, ab, affine);
    k_demod <<<dim3(Fn / 256, Bn),        256, 0, stream>>>(kw, affine, demod);
    k_tk    <<<dim3(Cn / 32, Fn / 64, 3), 256, 0, stream>>>(kw, kt);
    k_tx    <<<dim3(Wn / 64, Cn / 64, Bn),256, 0, stream>>>(content, affine, xt);
    k_conv  <<<dim3(Wn / BN, Fn / BM, Bn),256, 0, stream>>>(kt, xt, demod, kb, y);
}

// Round 2
// 229.436 us; speedup vs baseline: 1.0236x; 1.0236x over previous
//
#include <hip/hip_runtime.h>
#include <hip/hip_bf16.h>

#define Bn   16
#define LATn 512
#define Cn   512
#define Wn   4096
#define Fn   512

using bf16x8 = __attribute__((ext_vector_type(8))) short;
using f32x4  = __attribute__((ext_vector_type(4))) float;

__device__ __forceinline__ unsigned short f2bf(float x) {
    union { float f; unsigned int u; } v; v.f = x;
    unsigned int r = v.u + 0x7fffu + ((v.u >> 16) & 1u);
    return (unsigned short)(r >> 16);
}

__device__ __forceinline__ void gload_lds16(const void* g, void* l) {
    __builtin_amdgcn_global_load_lds(
        (const __attribute__((address_space(1))) unsigned int*)g,
        (__attribute__((address_space(3))) unsigned int*)l, 16, 0, 0);
}

// 1) affine[b][c] = latent[b,:] . affine_w[:,c] + affine_b[c]   (+ zero zbuf)
__global__ void k_affine(const float* __restrict__ latent,
                         const float* __restrict__ aw,
                         const float* __restrict__ ab,
                         float* __restrict__ affine,
                         float* __restrict__ zbuf) {
    if (blockIdx.x == 0 && blockIdx.y == 0 && threadIdx.x < 16)
        zbuf[threadIdx.x] = 0.f;
    const int c = blockIdx.x * 256 + threadIdx.x;
    const int b = blockIdx.y;
    float s0 = 0.f, s1 = 0.f;
    for (int l = 0; l < LATn; l += 2) {
        s0 = fmaf(latent[b * LATn + l],     aw[(size_t)l * Cn + c],       s0);
        s1 = fmaf(latent[b * LATn + l + 1], aw[(size_t)(l + 1) * Cn + c], s1);
    }
    affine[b * Cn + c] = s0 + s1 + ab[c];
}

// 2) demod[b][f] = rsqrt(sum_{k,c} kw[k][c][f]^2 * affine[b][c]^2 + 1e-8)
__global__ void k_demod(const float* __restrict__ kw,
                        const float* __restrict__ affine,
                        float* __restrict__ demod) {
    const int f = blockIdx.x * 256 + threadIdx.x;
    const int b = blockIdx.y;
    float s0 = 0.f, s1 = 0.f, s2 = 0.f;
    for (int c = 0; c < Cn; ++c) {
        const float a  = affine[b * Cn + c];
        const float a2 = a * a;
        const float k0 = kw[((size_t)(0 * Cn + c)) * Fn + f];
        const float k1 = kw[((size_t)(1 * Cn + c)) * Fn + f];
        const float k2 = kw[((size_t)(2 * Cn + c)) * Fn + f];
        s0 = fmaf(k0 * k0, a2, s0);
        s1 = fmaf(k1 * k1, a2, s1);
        s2 = fmaf(k2 * k2, a2, s2);
    }
    demod[b * Fn + f] = rsqrtf(s0 + s1 + s2 + 1e-8f);
}

// 3) kt[k][f][c] = bf16(kw[k][c][f])
__global__ void k_tk(const float* __restrict__ kw, unsigned short* __restrict__ kt) {
    __shared__ float lds[32][65];
    const int t  = threadIdx.x;
    const int k  = blockIdx.z;
    const int c0 = blockIdx.x * 32;
    const int f0 = blockIdx.y * 64;
    #pragma unroll
    for (int i = 0; i < 8; ++i) {
        int e = t + 256 * i; int c = e >> 6; int f = e & 63;
        lds[c][f] = kw[((size_t)(k * Cn + c0 + c)) * Fn + f0 + f];
    }
    __syncthreads();
    #pragma unroll
    for (int i = 0; i < 8; ++i) {
        int e = t + 256 * i; int f = e >> 5; int c = e & 31;
        kt[((size_t)(k * Fn + f0 + f)) * Cn + c0 + c] = f2bf(lds[c][f]);
    }
}

// 4) xt[b][w][c] = bf16(content[b][c][w] * affine[b][c])  — vectorized transpose
__global__ void k_tx(const float* __restrict__ content,
                     const float* __restrict__ affine,
                     unsigned short* __restrict__ xt) {
    __shared__ unsigned short lds[64][72];
    const int t  = threadIdx.x;
    const int b  = blockIdx.z;
    const int c0 = blockIdx.y * 64;
    const int w0 = blockIdx.x * 64;
    #pragma unroll
    for (int i = 0; i < 4; ++i) {
        int e = t + 256 * i;        // quad index, 0..1023
        int c = e >> 4;
        int w4 = (e & 15) * 4;
        float4 v = *(const float4*)&content[((size_t)(b * Cn + c0 + c)) * Wn + w0 + w4];
        float a = affine[b * Cn + c0 + c];
        lds[c][w4 + 0] = f2bf(v.x * a);
        lds[c][w4 + 1] = f2bf(v.y * a);
        lds[c][w4 + 2] = f2bf(v.z * a);
        lds[c][w4 + 3] = f2bf(v.w * a);
    }
    __syncthreads();
    #pragma unroll
    for (int i = 0; i < 2; ++i) {
        int e = t + 256 * i;        // 0..511
        int w = e >> 3;
        int c8 = (e & 7) * 8;
        unsigned short tmp[8];
        #pragma unroll
        for (int j = 0; j < 8; ++j) tmp[j] = lds[c8 + j][w];
        *(uint4*)&xt[((size_t)b * Wn + w0 + w) * Cn + c0 + c8] = *(uint4*)tmp;
    }
}

// 5) conv-GEMM via global_load_lds(16B) + chunk-XOR swizzled LDS
#define BM 128
#define BN 128
#define BK 32

__global__ __launch_bounds__(256, 4)
void k_conv(const unsigned short* __restrict__ kt,
            const unsigned short* __restrict__ xt,
            const float* __restrict__ demod,
            const float* __restrict__ kb,
            const float* __restrict__ zbuf,
            float* __restrict__ y) {
    __shared__ __align__(16) unsigned short klds[3][BM][BK];   // 24576 B, linear
    __shared__ __align__(16) unsigned short xlds[BN + 2][BK];  //  8320 B, linear

    const int t  = threadIdx.x;
    const int w0 = blockIdx.x * BN;
    const int f0 = blockIdx.y * BM;
    const int b  = blockIdx.z;

    const int wave = t >> 6;
    const int lane = t & 63;
    const int wr   = wave >> 1;
    const int wc   = wave & 1;
    const int l15  = lane & 15;
    const int lhi  = lane >> 4;

    f32x4 acc[4][4];
    #pragma unroll
    for (int m = 0; m < 4; ++m)
        #pragma unroll
        for (int n = 0; n < 4; ++n)
            #pragma unroll
            for (int r = 0; r < 4; ++r)
                acc[m][n][r] = 0.f;

    for (int cc = 0; cc < Cn / BK; ++cc) {
        const int c0 = cc * BK;

        // stage klds: 3*128*4 = 1536 chunks of 16B; 6 issues/wave.
        // LDS chunk (r, j') holds global chunk j = j' ^ (r&3)  (bank swizzle)
        #pragma unroll
        for (int i = 0; i < 6; ++i) {
            const int Q   = wave * 64 + 256 * i + lane;
            const int k   = Q >> 9;
            const int rem = Q & 511;
            const int r   = rem >> 2;
            const int j   = (rem & 3) ^ (r & 3);
            const unsigned short* src = &kt[((size_t)(k * Fn + f0 + r)) * Cn + c0 + j * 8];
            gload_lds16(src, (unsigned short*)klds + (size_t)(wave * 64 + 256 * i) * 8);
        }
        // stage xlds rows 0..127 (wg = w0-1+r), swizzled the same way
        #pragma unroll
        for (int i = 0; i < 2; ++i) {
            const int Q = wave * 64 + 256 * i + lane;
            const int r = Q >> 2;
            const int j = (Q & 3) ^ (r & 3);
            const int wg = w0 - 1 + r;
            const unsigned short* src = ((unsigned)wg < (unsigned)Wn)
                ? &xt[((size_t)b * Wn + wg) * Cn + c0 + j * 8]
                : (const unsigned short*)zbuf;
            gload_lds16(src, (unsigned short*)xlds + (size_t)(wave * 64 + 256 * i) * 8);
        }
        // tail rows 128,129 (8 chunks) by wave 0 lanes 0..7
        if (wave == 0 && lane < 8) {
            const int r = 128 + (lane >> 2);
            const int j = (lane & 3) ^ (r & 3);
            const int wg = w0 - 1 + r;
            const unsigned short* src = ((unsigned)wg < (unsigned)Wn)
                ? &xt[((size_t)b * Wn + wg) * Cn + c0 + j * 8]
                : (const unsigned short*)zbuf;
            gload_lds16(src, &xlds[128][0]);
        }
        __syncthreads();

        #pragma unroll
        for (int k = 0; k < 3; ++k) {
            bf16x8 af[4];
            #pragma unroll
            for (int m = 0; m < 4; ++m) {
                const int r = wr * 64 + m * 16 + l15;
                af[m] = *(const bf16x8*)&klds[k][r][(lhi ^ (r & 3)) * 8];
            }
            #pragma unroll
            for (int n = 0; n < 4; ++n) {
                const int rw = wc * 64 + n * 16 + l15 + k;
                const bf16x8 bv = *(const bf16x8*)&xlds[rw][(lhi ^ (rw & 3)) * 8];
                #pragma unroll
                for (int m = 0; m < 4; ++m)
                    acc[m][n] = __builtin_amdgcn_mfma_f32_16x16x32_bf16(af[m], bv, acc[m][n], 0, 0, 0);
            }
        }
        __syncthreads();
    }

    // epilogue: demod * acc + kb, leaky_relu(0.2)
    #pragma unroll
    for (int m = 0; m < 4; ++m) {
        const int fb = f0 + wr * 64 + m * 16 + lhi * 4;
        const float4 dmv = *(const float4*)&demod[b * Fn + fb];
        const float4 kbv = *(const float4*)&kb[fb];
        const float dmf[4] = {dmv.x, dmv.y, dmv.z, dmv.w};
        const float kbf[4] = {kbv.x, kbv.y, kbv.z, kbv.w};
        #pragma unroll
        for (int n = 0; n < 4; ++n) {
            const int w = w0 + wc * 64 + n * 16 + l15;
            #pragma unroll
            for (int r = 0; r < 4; ++r) {
                float v = fmaf(acc[m][n][r], dmf[r], kbf[r]);
                v = (v >= 0.f) ? v : 0.2f * v;
                y[((size_t)(b * Fn + fb + r)) * Wn + w] = v;
            }
        }
    }
}

extern "C" void kernel_launch(void* const* d_in, const int* in_sizes, int n_in,
                              void* d_out, int out_size, void* d_ws, size_t ws_size,
                              hipStream_t stream) {
    const float* latent  = (const float*)d_in[0];
    const float* content = (const float*)d_in[1];
    const float* aw      = (const float*)d_in[2];
    const float* ab      = (const float*)d_in[3];
    const float* kw      = (const float*)d_in[4];
    const float* kb      = (const float*)d_in[5];
    float* y = (float*)d_out;

    char* ws = (char*)d_ws;
    float*          affine = (float*)(ws);                        // 32 KB
    float*          demod  = (float*)(ws + 32768);                // 32 KB
    float*          zbuf   = (float*)(ws + 65536);                // 64 B (zeroed)
    unsigned short* kt     = (unsigned short*)(ws + 131072);      // 1.5 MB
    unsigned short* xt     = (unsigned short*)(ws + 2u * 1024u * 1024u); // 64 MB
    if (ws_size < 2u * 1024u * 1024u + (size_t)Bn * Wn * Cn * 2u) return;

    k_affine<<<dim3(Cn / 256, Bn),         256, 0, stream>>>(latent, aw, ab, affine, zbuf);
    k_demod <<<dim3(Fn / 256, Bn),         256, 0, stream>>>(kw, affine, demod);
    k_tk    <<<dim3(Cn / 32, Fn / 64, 3),  256, 0, stream>>>(kw, kt);
    k_tx    <<<dim3(Wn / 64, Cn / 64, Bn), 256, 0, stream>>>(content, affine, xt);
    k_conv  <<<dim3(Wn / BN, Fn / BM, Bn), 256, 0, stream>>>(kt, xt, demod, kb, zbuf, y);
}

// Round 3
// 225.960 us; speedup vs baseline: 1.0394x; 1.0154x over previous
//
#include <hip/hip_runtime.h>
#include <hip/hip_bf16.h>

#define Bn   16
#define LATn 512
#define Cn   512
#define Wn   4096
#define Fn   512

using bf16x8 = __attribute__((ext_vector_type(8))) short;
using f32x4  = __attribute__((ext_vector_type(4))) float;

__device__ __forceinline__ unsigned short f2bf(float x) {
    union { float f; unsigned int u; } v; v.f = x;
    unsigned int r = v.u + 0x7fffu + ((v.u >> 16) & 1u);
    return (unsigned short)(r >> 16);
}

__device__ __forceinline__ void gload_lds16(const void* g, void* l) {
    __builtin_amdgcn_global_load_lds(
        (const __attribute__((address_space(1))) unsigned int*)g,
        (__attribute__((address_space(3))) unsigned int*)l, 16, 0, 0);
}

// 1) affine[b][c] = latent[b,:] . affine_w[:,c] + affine_b[c]   (+ zero zbuf)
__global__ void k_affine(const float* __restrict__ latent,
                         const float* __restrict__ aw,
                         const float* __restrict__ ab,
                         float* __restrict__ affine,
                         float* __restrict__ zbuf) {
    if (blockIdx.x == 0 && blockIdx.y == 0 && threadIdx.x < 16)
        zbuf[threadIdx.x] = 0.f;
    const int c = blockIdx.x * 256 + threadIdx.x;
    const int b = blockIdx.y;
    float s0 = 0.f, s1 = 0.f;
    for (int l = 0; l < LATn; l += 2) {
        s0 = fmaf(latent[b * LATn + l],     aw[(size_t)l * Cn + c],       s0);
        s1 = fmaf(latent[b * LATn + l + 1], aw[(size_t)(l + 1) * Cn + c], s1);
    }
    affine[b * Cn + c] = s0 + s1 + ab[c];
}

// 2) demod[b][f] = rsqrt(sum_{k,c} kw[k][c][f]^2 * affine[b][c]^2 + 1e-8)
__global__ void k_demod(const float* __restrict__ kw,
                        const float* __restrict__ affine,
                        float* __restrict__ demod) {
    const int f = blockIdx.x * 256 + threadIdx.x;
    const int b = blockIdx.y;
    float s0 = 0.f, s1 = 0.f, s2 = 0.f;
    for (int c = 0; c < Cn; ++c) {
        const float a  = affine[b * Cn + c];
        const float a2 = a * a;
        const float k0 = kw[((size_t)(0 * Cn + c)) * Fn + f];
        const float k1 = kw[((size_t)(1 * Cn + c)) * Fn + f];
        const float k2 = kw[((size_t)(2 * Cn + c)) * Fn + f];
        s0 = fmaf(k0 * k0, a2, s0);
        s1 = fmaf(k1 * k1, a2, s1);
        s2 = fmaf(k2 * k2, a2, s2);
    }
    demod[b * Fn + f] = rsqrtf(s0 + s1 + s2 + 1e-8f);
}

// 3) kt[k][f][c] = bf16(kw[k][c][f])
__global__ void k_tk(const float* __restrict__ kw, unsigned short* __restrict__ kt) {
    __shared__ float lds[32][65];
    const int t  = threadIdx.x;
    const int k  = blockIdx.z;
    const int c0 = blockIdx.x * 32;
    const int f0 = blockIdx.y * 64;
    #pragma unroll
    for (int i = 0; i < 8; ++i) {
        int e = t + 256 * i; int c = e >> 6; int f = e & 63;
        lds[c][f] = kw[((size_t)(k * Cn + c0 + c)) * Fn + f0 + f];
    }
    __syncthreads();
    #pragma unroll
    for (int i = 0; i < 8; ++i) {
        int e = t + 256 * i; int f = e >> 5; int c = e & 31;
        kt[((size_t)(k * Fn + f0 + f)) * Cn + c0 + c] = f2bf(lds[c][f]);
    }
}

// 4) xt[b][w][c] = bf16(content[b][c][w] * affine[b][c])
//    LDS: stride-74 rows + w^=((c>>3)<<3) swizzle -> both phases <=2-way (free)
__global__ void k_tx(const float* __restrict__ content,
                     const float* __restrict__ affine,
                     unsigned short* __restrict__ xt) {
    __shared__ unsigned short lds[64][74];
    const int t  = threadIdx.x;
    const int b  = blockIdx.z;
    const int c0 = blockIdx.y * 64;
    const int w0 = blockIdx.x * 64;
    #pragma unroll
    for (int i = 0; i < 4; ++i) {
        int e = t + 256 * i;        // 0..1023
        int c = e >> 4;
        int w4 = (e & 15) * 4;
        float4 v = *(const float4*)&content[((size_t)(b * Cn + c0 + c)) * Wn + w0 + w4];
        float a = affine[b * Cn + c0 + c];
        int wx = w4 ^ ((c >> 3) << 3);
        lds[c][wx + 0] = f2bf(v.x * a);
        lds[c][wx + 1] = f2bf(v.y * a);
        lds[c][wx + 2] = f2bf(v.z * a);
        lds[c][wx + 3] = f2bf(v.w * a);
    }
    __syncthreads();
    #pragma unroll
    for (int i = 0; i < 2; ++i) {
        int e = t + 256 * i;        // 0..511
        int w  = e >> 3;
        int q  = e & 7;
        int c8 = q * 8;
        int wx = w ^ (q << 3);
        unsigned short tmp[8];
        #pragma unroll
        for (int j = 0; j < 8; ++j) tmp[j] = lds[c8 + j][wx];
        *(uint4*)&xt[((size_t)b * Wn + w0 + w) * Cn + c0 + c8] = *(uint4*)tmp;
    }
}

// 5) conv-GEMM: BM=128 f, BN=256 w, BK=32, 4 waves each computing 64f x 128w
#define BM 128
#define BN 256
#define BK 32

__global__ __launch_bounds__(256, 2)
void k_conv(const unsigned short* __restrict__ kt,
            const unsigned short* __restrict__ xt,
            const float* __restrict__ demod,
            const float* __restrict__ kb,
            const float* __restrict__ zbuf,
            float* __restrict__ y) {
    __shared__ __align__(16) unsigned short klds[3][BM][BK];   // 24576 B
    __shared__ __align__(16) unsigned short xlds[BN + 2][BK];  // 16512 B

    const int t  = threadIdx.x;
    const int w0 = blockIdx.x * BN;
    const int f0 = blockIdx.y * BM;
    const int b  = blockIdx.z;

    const int wave = t >> 6;
    const int lane = t & 63;
    const int wm   = wave >> 1;   // f 64-half
    const int wn   = wave & 1;    // w 128-half
    const int l15  = lane & 15;
    const int lhi  = lane >> 4;

    f32x4 acc[4][8];
    #pragma unroll
    for (int m = 0; m < 4; ++m)
        #pragma unroll
        for (int n = 0; n < 8; ++n)
            #pragma unroll
            for (int r = 0; r < 4; ++r)
                acc[m][n][r] = 0.f;

    for (int cc = 0; cc < Cn / BK; ++cc) {
        const int c0 = cc * BK;

        // stage klds: 1536 16B chunks, 6 per thread. LDS[r][jl] = G[r][jl ^ ((r>>1)&3)]
        #pragma unroll
        for (int i = 0; i < 6; ++i) {
            const int Q   = wave * 64 + 256 * i + lane;
            const int k   = Q >> 9;
            const int r   = (Q >> 2) & 127;
            const int j   = (Q & 3) ^ ((r >> 1) & 3);
            const unsigned short* src = &kt[((size_t)(k * Fn + f0 + r)) * Cn + c0 + j * 8];
            gload_lds16(src, (unsigned short*)klds + (size_t)(wave * 64 + 256 * i) * 8);
        }
        // stage xlds rows 0..255 (wg = w0-1+r), same swizzle
        #pragma unroll
        for (int i = 0; i < 4; ++i) {
            const int Q = wave * 64 + 256 * i + lane;
            const int r = Q >> 2;
            const int j = (Q & 3) ^ ((r >> 1) & 3);
            const int wg = w0 - 1 + r;
            const unsigned short* src = ((unsigned)wg < (unsigned)Wn)
                ? &xt[((size_t)b * Wn + wg) * Cn + c0 + j * 8]
                : (const unsigned short*)zbuf;
            gload_lds16(src, (unsigned short*)xlds + (size_t)(wave * 64 + 256 * i) * 8);
        }
        // tail rows 256,257 (8 chunks) by wave 0 lanes 0..7
        if (wave == 0 && lane < 8) {
            const int r = 256 + (lane >> 2);
            const int j = (lane & 3) ^ ((r >> 1) & 3);
            const int wg = w0 - 1 + r;
            const unsigned short* src = ((unsigned)wg < (unsigned)Wn)
                ? &xt[((size_t)b * Wn + wg) * Cn + c0 + j * 8]
                : (const unsigned short*)zbuf;
            gload_lds16(src, (unsigned short*)xlds + (size_t)256 * 32);
        }
        __syncthreads();

        #pragma unroll
        for (int k = 0; k < 3; ++k) {
            bf16x8 af[4];
            #pragma unroll
            for (int m = 0; m < 4; ++m) {
                const int r = wm * 64 + m * 16 + l15;
                af[m] = *(const bf16x8*)&klds[k][r][(lhi ^ ((r >> 1) & 3)) * 8];
            }
            #pragma unroll
            for (int n = 0; n < 8; ++n) {
                const int rw = wn * 128 + n * 16 + l15 + k;
                const bf16x8 bv = *(const bf16x8*)&xlds[rw][(lhi ^ ((rw >> 1) & 3)) * 8];
                #pragma unroll
                for (int m = 0; m < 4; ++m)
                    acc[m][n] = __builtin_amdgcn_mfma_f32_16x16x32_bf16(af[m], bv, acc[m][n], 0, 0, 0);
            }
        }
        __syncthreads();
    }

    // epilogue: demod * acc + kb, leaky_relu(0.2)
    #pragma unroll
    for (int m = 0; m < 4; ++m) {
        const int fb = f0 + wm * 64 + m * 16 + lhi * 4;
        const float4 dmv = *(const float4*)&demod[b * Fn + fb];
        const float4 kbv = *(const float4*)&kb[fb];
        const float dmf[4] = {dmv.x, dmv.y, dmv.z, dmv.w};
        const float kbf[4] = {kbv.x, kbv.y, kbv.z, kbv.w};
        #pragma unroll
        for (int n = 0; n < 8; ++n) {
            const int w = w0 + wn * 128 + n * 16 + l15;
            #pragma unroll
            for (int r = 0; r < 4; ++r) {
                float v = fmaf(acc[m][n][r], dmf[r], kbf[r]);
                v = (v >= 0.f) ? v : 0.2f * v;
                y[((size_t)(b * Fn + fb + r)) * Wn + w] = v;
            }
        }
    }
}

extern "C" void kernel_launch(void* const* d_in, const int* in_sizes, int n_in,
                              void* d_out, int out_size, void* d_ws, size_t ws_size,
                              hipStream_t stream) {
    const float* latent  = (const float*)d_in[0];
    const float* content = (const float*)d_in[1];
    const float* aw      = (const float*)d_in[2];
    const float* ab      = (const float*)d_in[3];
    const float* kw      = (const float*)d_in[4];
    const float* kb      = (const float*)d_in[5];
    float* y = (float*)d_out;

    char* ws = (char*)d_ws;
    float*          affine = (float*)(ws);                        // 32 KB
    float*          demod  = (float*)(ws + 32768);                // 32 KB
    float*          zbuf   = (float*)(ws + 65536);                // 64 B (zeroed)
    unsigned short* kt     = (unsigned short*)(ws + 131072);      // 1.5 MB
    unsigned short* xt     = (unsigned short*)(ws + 2u * 1024u * 1024u); // 64 MB
    if (ws_size < 2u * 1024u * 1024u + (size_t)Bn * Wn * Cn * 2u) return;

    k_affine<<<dim3(Cn / 256, Bn),         256, 0, stream>>>(latent, aw, ab, affine, zbuf);
    k_demod <<<dim3(Fn / 256, Bn),         256, 0, stream>>>(kw, affine, demod);
    k_tk    <<<dim3(Cn / 32, Fn / 64, 3),  256, 0, stream>>>(kw, kt);
    k_tx    <<<dim3(Wn / 64, Cn / 64, Bn), 256, 0, stream>>>(content, affine, xt);
    k_conv  <<<dim3(Wn / BN, Fn / BM, Bn), 256, 0, stream>>>(kt, xt, demod, kb, zbuf, y);
}

// Round 4
// 175.825 us; speedup vs baseline: 1.3357x; 1.2851x over previous
//
#include <hip/hip_runtime.h>
#include <hip/hip_bf16.h>

#define Bn   16
#define LATn 512
#define Cn   512
#define Wn   4096
#define Fn   512

using bf16x8 = __attribute__((ext_vector_type(8))) short;
using f32x4  = __attribute__((ext_vector_type(4))) float;

__device__ __forceinline__ unsigned short f2bf(float x) {
    union { float f; unsigned int u; } v; v.f = x;
    unsigned int r = v.u + 0x7fffu + ((v.u >> 16) & 1u);
    return (unsigned short)(r >> 16);
}

__device__ __forceinline__ void gload_lds16(const void* g, void* l) {
    __builtin_amdgcn_global_load_lds(
        (const __attribute__((address_space(1))) unsigned int*)g,
        (__attribute__((address_space(3))) unsigned int*)l, 16, 0, 0);
}

// 1) affine[b][c] = latent[b,:] . affine_w[:,c] + affine_b[c]   (+ zero zbuf)
__global__ void k_affine(const float* __restrict__ latent,
                         const float* __restrict__ aw,
                         const float* __restrict__ ab,
                         float* __restrict__ affine,
                         float* __restrict__ zbuf) {
    if (blockIdx.x == 0 && blockIdx.y == 0 && threadIdx.x < 16)
        zbuf[threadIdx.x] = 0.f;
    const int c = blockIdx.x * 256 + threadIdx.x;
    const int b = blockIdx.y;
    float s0 = 0.f, s1 = 0.f;
    for (int l = 0; l < LATn; l += 2) {
        s0 = fmaf(latent[b * LATn + l],     aw[(size_t)l * Cn + c],       s0);
        s1 = fmaf(latent[b * LATn + l + 1], aw[(size_t)(l + 1) * Cn + c], s1);
    }
    affine[b * Cn + c] = s0 + s1 + ab[c];
}

// 2a) Q[c][f] = sum_k kw[k][c][f]^2   (fully coalesced, float4)
__global__ void k_qsum(const float* __restrict__ kw, float* __restrict__ Q) {
    const int i = (blockIdx.x * 256 + threadIdx.x) * 4;
    const float4 a = *(const float4*)&kw[i];
    const float4 b = *(const float4*)&kw[Cn * Fn + i];
    const float4 c = *(const float4*)&kw[2 * Cn * Fn + i];
    float4 q;
    q.x = a.x * a.x + b.x * b.x + c.x * c.x;
    q.y = a.y * a.y + b.y * b.y + c.y * c.y;
    q.z = a.z * a.z + b.z * b.z + c.z * c.z;
    q.w = a.w * a.w + b.w * b.w + c.w * c.w;
    *(float4*)&Q[i] = q;
}

// 2b) demod[b][f] = rsqrt(sum_c affine[b][c]^2 * Q[c][f] + 1e-8)
__global__ void k_demod2(const float* __restrict__ Q,
                         const float* __restrict__ affine,
                         float* __restrict__ demod) {
    const int f = blockIdx.x * 256 + threadIdx.x;
    const int b = blockIdx.y;
    float s0 = 0.f, s1 = 0.f, s2 = 0.f, s3 = 0.f;
    for (int c = 0; c < Cn; c += 4) {
        const float a0 = affine[b * Cn + c + 0];
        const float a1 = affine[b * Cn + c + 1];
        const float a2 = affine[b * Cn + c + 2];
        const float a3 = affine[b * Cn + c + 3];
        s0 = fmaf(a0 * a0, Q[(size_t)(c + 0) * Fn + f], s0);
        s1 = fmaf(a1 * a1, Q[(size_t)(c + 1) * Fn + f], s1);
        s2 = fmaf(a2 * a2, Q[(size_t)(c + 2) * Fn + f], s2);
        s3 = fmaf(a3 * a3, Q[(size_t)(c + 3) * Fn + f], s3);
    }
    demod[b * Fn + f] = rsqrtf(s0 + s1 + s2 + s3 + 1e-8f);
}

// 3) kt[k][f][c] = bf16(kw[k][c][f])
__global__ void k_tk(const float* __restrict__ kw, unsigned short* __restrict__ kt) {
    __shared__ float lds[32][65];
    const int t  = threadIdx.x;
    const int k  = blockIdx.z;
    const int c0 = blockIdx.x * 32;
    const int f0 = blockIdx.y * 64;
    #pragma unroll
    for (int i = 0; i < 8; ++i) {
        int e = t + 256 * i; int c = e >> 6; int f = e & 63;
        lds[c][f] = kw[((size_t)(k * Cn + c0 + c)) * Fn + f0 + f];
    }
    __syncthreads();
    #pragma unroll
    for (int i = 0; i < 8; ++i) {
        int e = t + 256 * i; int f = e >> 5; int c = e & 31;
        kt[((size_t)(k * Fn + f0 + f)) * Cn + c0 + c] = f2bf(lds[c][f]);
    }
}

// 4) xt[b][w][c] = bf16(content[b][c][w] * affine[b][c])
//    stride-72 rows (8B-aligned) + w^=((c>>3)<<3) swizzle; both phases <=2-way
__global__ void k_tx(const float* __restrict__ content,
                     const float* __restrict__ affine,
                     unsigned short* __restrict__ xt) {
    __shared__ unsigned short lds[64][72];
    const int t  = threadIdx.x;
    const int b  = blockIdx.z;
    const int c0 = blockIdx.y * 64;
    const int w0 = blockIdx.x * 64;
    #pragma unroll
    for (int i = 0; i < 4; ++i) {
        int e = t + 256 * i;        // 0..1023
        int c = e >> 4;
        int w4 = (e & 15) * 4;
        float4 v = *(const float4*)&content[((size_t)(b * Cn + c0 + c)) * Wn + w0 + w4];
        float a = affine[b * Cn + c0 + c];
        int wx = w4 ^ ((c >> 3) << 3);
        unsigned short p[4] = {f2bf(v.x * a), f2bf(v.y * a), f2bf(v.z * a), f2bf(v.w * a)};
        *(uint2*)&lds[c][wx] = *(const uint2*)p;
    }
    __syncthreads();
    #pragma unroll
    for (int i = 0; i < 2; ++i) {
        int e = t + 256 * i;        // 0..511
        int w  = e >> 3;
        int q  = e & 7;
        int c8 = q * 8;
        int wx = w ^ (q << 3);
        unsigned short tmp[8];
        #pragma unroll
        for (int j = 0; j < 8; ++j) tmp[j] = lds[c8 + j][wx];
        *(uint4*)&xt[((size_t)b * Wn + w0 + w) * Cn + c0 + c8] = *(uint4*)tmp;
    }
}

// 5) conv-GEMM: 256f x 256w tile, BK=32, 8 waves (2f x 4w), dbuf LDS pipeline
#define BM 256
#define BN 256
#define BK 32
#define KBYTES (3 * BM * BK * 2)            // 49152 per buffer
#define BUFB   (KBYTES + BN * BK * 2)       // 65536 per buffer
#define SMEMB  (2 * BUFB + 2 * Cn * 2)      // 133120 total

__device__ __forceinline__ void stage_step(
    const unsigned short* __restrict__ kt, const unsigned short* __restrict__ xt,
    char* dst, int t, int f0, int w0, int b, int c0s) {
    #pragma unroll
    for (int i = 0; i < 6; ++i) {
        const int Q = i * 512 + t;
        const int k = Q >> 10;
        const int r = (Q >> 2) & 255;
        const int j = (Q & 3) ^ ((r >> 1) & 3);
        gload_lds16(&kt[((size_t)(k * Fn + f0 + r)) * Cn + c0s + j * 8],
                    dst + (size_t)Q * 16);
    }
    #pragma unroll
    for (int i = 0; i < 2; ++i) {
        const int Q = i * 512 + t;
        const int r = Q >> 2;
        const int j = (Q & 3) ^ ((r >> 1) & 3);
        gload_lds16(&xt[((size_t)b * Wn + w0 + r) * Cn + c0s + j * 8],
                    dst + KBYTES + (size_t)Q * 16);
    }
}

extern __shared__ __align__(16) char smem[];

__global__ __launch_bounds__(512, 2)
void k_conv(const unsigned short* __restrict__ kt,
            const unsigned short* __restrict__ xt,
            const float* __restrict__ demod,
            const float* __restrict__ kb,
            const float* __restrict__ zbuf,
            float* __restrict__ y) {
    const int t  = threadIdx.x;
    const int w0 = blockIdx.x * BN;
    const int f0 = blockIdx.y * BM;
    const int b  = blockIdx.z;

    const int wave = t >> 6;
    const int lane = t & 63;
    const int wm   = wave >> 2;   // f-half (128)
    const int wn   = wave & 3;    // w-quarter (64)
    const int l15  = lane & 15;
    const int lhi  = lane >> 4;

    unsigned short* halo = (unsigned short*)(smem + 2 * BUFB); // [2][512]

    f32x4 acc[8][4];
    #pragma unroll
    for (int m = 0; m < 8; ++m)
        #pragma unroll
        for (int n = 0; n < 4; ++n)
            #pragma unroll
            for (int r = 0; r < 4; ++r)
                acc[m][n][r] = 0.f;

    // prologue: halo rows (w0-1, w0+BN) across all 512 c, plus stage tile 0
    if (t < 128) {
        const int h  = t >> 6;
        const int j  = t & 63;
        const int wg = h ? (w0 + BN) : (w0 - 1);
        const unsigned short* src = ((unsigned)wg < (unsigned)Wn)
            ? &xt[((size_t)b * Wn + wg) * Cn + j * 8]
            : (const unsigned short*)zbuf;
        gload_lds16(src, halo + (size_t)t * 8);
    }
    stage_step(kt, xt, smem, t, f0, w0, b, 0);
    __syncthreads();

    int cur = 0;
    for (int cc = 0; cc < Cn / BK; ++cc) {
        char* bufc = smem + cur * BUFB;
        const unsigned short* ka = (const unsigned short*)bufc;          // [3][256][32]
        const unsigned short* xa = (const unsigned short*)(bufc + KBYTES); // [256][32]
        if (cc < Cn / BK - 1)
            stage_step(kt, xt, smem + (cur ^ 1) * BUFB, t, f0, w0, b, (cc + 1) * BK);
        const int c0 = cc * BK;

        #pragma unroll
        for (int k = 0; k < 3; ++k) {
            bf16x8 af[8];
            #pragma unroll
            for (int m = 0; m < 8; ++m) {
                const int r = wm * 128 + m * 16 + l15;
                af[m] = *(const bf16x8*)(ka + (k * 256 + r) * 32 + (lhi ^ ((r >> 1) & 3)) * 8);
            }
            bf16x8 bv[4];
            #pragma unroll
            for (int n = 0; n < 4; ++n) {
                const int rl = wn * 64 + n * 16 + l15 + k - 1;
                const unsigned short* bp;
                if (k == 0 && n == 0) {
                    bp = (rl < 0) ? (halo + c0 + lhi * 8)
                                  : (xa + rl * 32 + (lhi ^ ((rl >> 1) & 3)) * 8);
                } else if (k == 2 && n == 3) {
                    bp = (rl > 255) ? (halo + 512 + c0 + lhi * 8)
                                    : (xa + rl * 32 + (lhi ^ ((rl >> 1) & 3)) * 8);
                } else {
                    bp = xa + rl * 32 + (lhi ^ ((rl >> 1) & 3)) * 8;
                }
                bv[n] = *(const bf16x8*)bp;
            }
            __builtin_amdgcn_s_setprio(1);
            #pragma unroll
            for (int n = 0; n < 4; ++n)
                #pragma unroll
                for (int m = 0; m < 8; ++m)
                    acc[m][n] = __builtin_amdgcn_mfma_f32_16x16x32_bf16(af[m], bv[n], acc[m][n], 0, 0, 0);
            __builtin_amdgcn_s_setprio(0);
        }
        __syncthreads();
        cur ^= 1;
    }

    // epilogue: demod * acc + kb, leaky_relu(0.2)
    #pragma unroll
    for (int m = 0; m < 8; ++m) {
        const int fb = f0 + wm * 128 + m * 16 + lhi * 4;
        const float4 dmv = *(const float4*)&demod[b * Fn + fb];
        const float4 kbv = *(const float4*)&kb[fb];
        const float dmf[4] = {dmv.x, dmv.y, dmv.z, dmv.w};
        const float kbf[4] = {kbv.x, kbv.y, kbv.z, kbv.w};
        #pragma unroll
        for (int n = 0; n < 4; ++n) {
            const int w = w0 + wn * 64 + n * 16 + l15;
            #pragma unroll
            for (int r = 0; r < 4; ++r) {
                float v = fmaf(acc[m][n][r], dmf[r], kbf[r]);
                v = (v >= 0.f) ? v : 0.2f * v;
                y[((size_t)(b * Fn + fb + r)) * Wn + w] = v;
            }
        }
    }
}

extern "C" void kernel_launch(void* const* d_in, const int* in_sizes, int n_in,
                              void* d_out, int out_size, void* d_ws, size_t ws_size,
                              hipStream_t stream) {
    const float* latent  = (const float*)d_in[0];
    const float* content = (const float*)d_in[1];
    const float* aw      = (const float*)d_in[2];
    const float* ab      = (const float*)d_in[3];
    const float* kw      = (const float*)d_in[4];
    const float* kb      = (const float*)d_in[5];
    float* y = (float*)d_out;

    char* ws = (char*)d_ws;
    float*          affine = (float*)(ws);                        // 32 KB
    float*          demod  = (float*)(ws + 32768);                // 32 KB
    float*          zbuf   = (float*)(ws + 65536);                // 64 B (zeroed)
    float*          Q      = (float*)(ws + 131072);               // 1 MB (aliases kt, used before k_tk)
    unsigned short* kt     = (unsigned short*)(ws + 131072);      // 1.5 MB
    unsigned short* xt     = (unsigned short*)(ws + 2u * 1024u * 1024u); // 64 MB
    if (ws_size < 2u * 1024u * 1024u + (size_t)Bn * Wn * Cn * 2u) return;

    hipFuncSetAttribute((const void*)k_conv,
                        hipFuncAttributeMaxDynamicSharedMemorySize, SMEMB);

    k_affine<<<dim3(Cn / 256, Bn),          256, 0, stream>>>(latent, aw, ab, affine, zbuf);
    k_qsum  <<<dim3(Cn * Fn / 1024),        256, 0, stream>>>(kw, Q);
    k_demod2<<<dim3(Fn / 256, Bn),          256, 0, stream>>>(Q, affine, demod);
    k_tk    <<<dim3(Cn / 32, Fn / 64, 3),   256, 0, stream>>>(kw, kt);
    k_tx    <<<dim3(Wn / 64, Cn / 64, Bn),  256, 0, stream>>>(content, affine, xt);
    k_conv  <<<dim3(Wn / BN, Fn / BM, Bn),  512, SMEMB, stream>>>(kt, xt, demod, kb, zbuf, y);
}

// Round 5
// 167.060 us; speedup vs baseline: 1.4058x; 1.0525x over previous
//
#include <hip/hip_runtime.h>
#include <hip/hip_bf16.h>

#define Bn   16
#define LATn 512
#define Cn   512
#define Wn   4096
#define Fn   512

using bf16x8 = __attribute__((ext_vector_type(8))) short;
using f32x4  = __attribute__((ext_vector_type(4))) float;

__device__ __forceinline__ unsigned short f2bf(float x) {
    union { float f; unsigned int u; } v; v.f = x;
    unsigned int r = v.u + 0x7fffu + ((v.u >> 16) & 1u);
    return (unsigned short)(r >> 16);
}

__device__ __forceinline__ void gload_lds16(const void* g, void* l) {
    __builtin_amdgcn_global_load_lds(
        (const __attribute__((address_space(1))) unsigned int*)g,
        (__attribute__((address_space(3))) unsigned int*)l, 16, 0, 0);
}

// 1) affine[b][c] = latent . aw[:,c] + ab[c]; 128 blocks, split-K over l
__global__ void k_affine(const float* __restrict__ latent,
                         const float* __restrict__ aw,
                         const float* __restrict__ ab,
                         float* __restrict__ affine,
                         float* __restrict__ zbuf) {
    if (blockIdx.x == 0 && blockIdx.y == 0 && threadIdx.x < 16)
        zbuf[threadIdx.x] = 0.f;
    __shared__ float red[4][64];
    const int t  = threadIdx.x;
    const int cl = t & 63, lq = t >> 6;
    const int c  = blockIdx.x * 64 + cl;
    const int b  = blockIdx.y;
    float s = 0.f;
    #pragma unroll 4
    for (int l = lq * 128; l < lq * 128 + 128; ++l)
        s = fmaf(latent[b * LATn + l], aw[(size_t)l * Cn + c], s);
    red[lq][cl] = s;
    __syncthreads();
    if (t < 64)
        affine[b * Cn + blockIdx.x * 64 + t] =
            red[0][t] + red[1][t] + red[2][t] + red[3][t] + ab[blockIdx.x * 64 + t];
}

// 2a) Q[c][f] = sum_k kw[k][c][f]^2
__global__ void k_qsum(const float* __restrict__ kw, float* __restrict__ Q) {
    const int i = (blockIdx.x * 256 + threadIdx.x) * 4;
    const float4 a = *(const float4*)&kw[i];
    const float4 b = *(const float4*)&kw[Cn * Fn + i];
    const float4 c = *(const float4*)&kw[2 * Cn * Fn + i];
    float4 q;
    q.x = a.x * a.x + b.x * b.x + c.x * c.x;
    q.y = a.y * a.y + b.y * b.y + c.y * c.y;
    q.z = a.z * a.z + b.z * b.z + c.z * c.z;
    q.w = a.w * a.w + b.w * b.w + c.w * c.w;
    *(float4*)&Q[i] = q;
}

// 2b) demod[b][f] = rsqrt(sum_c affine^2 * Q[c][f] + 1e-8); 128 blocks, split-K
__global__ void k_demod2(const float* __restrict__ Q,
                         const float* __restrict__ affine,
                         float* __restrict__ demod) {
    __shared__ float red[4][64];
    const int t  = threadIdx.x;
    const int fl = t & 63, cq = t >> 6;
    const int f  = blockIdx.x * 64 + fl;
    const int b  = blockIdx.y;
    float s = 0.f;
    #pragma unroll 4
    for (int c = cq * 128; c < cq * 128 + 128; ++c) {
        const float a = affine[b * Cn + c];
        s = fmaf(a * a, Q[(size_t)c * Fn + f], s);
    }
    red[cq][fl] = s;
    __syncthreads();
    if (t < 64)
        demod[b * Fn + blockIdx.x * 64 + t] =
            rsqrtf(red[0][t] + red[1][t] + red[2][t] + red[3][t] + 1e-8f);
}

// 3) kt[k][f][c] = bf16(kw[k][c][f])
__global__ void k_tk(const float* __restrict__ kw, unsigned short* __restrict__ kt) {
    __shared__ float lds[32][65];
    const int t  = threadIdx.x;
    const int k  = blockIdx.z;
    const int c0 = blockIdx.x * 32;
    const int f0 = blockIdx.y * 64;
    #pragma unroll
    for (int i = 0; i < 8; ++i) {
        int e = t + 256 * i; int c = e >> 6; int f = e & 63;
        lds[c][f] = kw[((size_t)(k * Cn + c0 + c)) * Fn + f0 + f];
    }
    __syncthreads();
    #pragma unroll
    for (int i = 0; i < 8; ++i) {
        int e = t + 256 * i; int f = e >> 5; int c = e & 31;
        kt[((size_t)(k * Fn + f0 + f)) * Cn + c0 + c] = f2bf(lds[c][f]);
    }
}

// 4) xt[b][w][c] = bf16(content[b][c][w] * affine[b][c])
__global__ void k_tx(const float* __restrict__ content,
                     const float* __restrict__ affine,
                     unsigned short* __restrict__ xt) {
    __shared__ unsigned short lds[64][72];
    const int t  = threadIdx.x;
    const int b  = blockIdx.z;
    const int c0 = blockIdx.y * 64;
    const int w0 = blockIdx.x * 64;
    #pragma unroll
    for (int i = 0; i < 4; ++i) {
        int e = t + 256 * i;
        int c = e >> 4;
        int w4 = (e & 15) * 4;
        float4 v = *(const float4*)&content[((size_t)(b * Cn + c0 + c)) * Wn + w0 + w4];
        float a = affine[b * Cn + c0 + c];
        int wx = w4 ^ ((c >> 3) << 3);
        unsigned short p[4] = {f2bf(v.x * a), f2bf(v.y * a), f2bf(v.z * a), f2bf(v.w * a)};
        *(uint2*)&lds[c][wx] = *(const uint2*)p;
    }
    __syncthreads();
    #pragma unroll
    for (int i = 0; i < 2; ++i) {
        int e = t + 256 * i;
        int w  = e >> 3;
        int q  = e & 7;
        int c8 = q * 8;
        int wx = w ^ (q << 3);
        unsigned short tmp[8];
        #pragma unroll
        for (int j = 0; j < 8; ++j) tmp[j] = lds[c8 + j][wx];
        *(uint4*)&xt[((size_t)b * Wn + w0 + w) * Cn + c0 + c8] = *(uint4*)tmp;
    }
}

// 5) conv-GEMM: 256f x 256w, BK=32, 8 waves, 3 phases/K-tile, counted vmcnt
#define BM 256
#define BN 256
#define BK 32
#define KBYTES (3 * BM * BK * 2)            // 49152 per buffer
#define BUFB   (KBYTES + BN * BK * 2)       // 65536 per buffer
#define SMEMB  (2 * BUFB + 2 * Cn * 2)      // 133120 total

extern __shared__ __align__(16) char smem[];

// 2 xt chunks per thread for K-slice c0s into buffer dst
#define ISSUE_XT(dst, c0s) { \
    _Pragma("unroll") for (int i_ = 0; i_ < 2; ++i_) { \
        const int Q_ = i_ * 512 + t; \
        const int r_ = Q_ >> 2; \
        const int j_ = (Q_ & 3) ^ ((r_ >> 1) & 3); \
        gload_lds16(&xt[((size_t)b * Wn + w0 + r_) * Cn + (c0s) + j_ * 8], \
                    (dst) + KBYTES + (size_t)Q_ * 16); } }

// 2 kt chunks (plane P) per thread
#define ISSUE_PLANE(dst, c0s, P) { \
    _Pragma("unroll") for (int i_ = 0; i_ < 2; ++i_) { \
        const int Q_ = i_ * 512 + t; \
        const int r_ = Q_ >> 2; \
        const int j_ = (Q_ & 3) ^ ((r_ >> 1) & 3); \
        gload_lds16(&kt[((size_t)((P) * Fn + f0 + r_)) * Cn + (c0s) + j_ * 8], \
                    (dst) + (size_t)((P) * 1024 + Q_) * 16); } }

// one phase = k-tap K: vmcnt(VM) -> barrier -> 12 ds_read -> prefetch issue ->
// lgkmcnt(0)+sched_barrier -> setprio-wrapped 32 MFMA
#define PHASE(K, VM, ...) { \
    asm volatile("s_waitcnt vmcnt(" #VM ")" ::: "memory"); \
    asm volatile("s_barrier" ::: "memory"); \
    bf16x8 af[8]; bf16x8 bv[4]; \
    _Pragma("unroll") for (int m_ = 0; m_ < 8; ++m_) { \
        const int r_ = wm * 128 + m_ * 16 + l15; \
        af[m_] = *(const bf16x8*)(ka + ((K) * 256 + r_) * 32 + (lhi ^ ((r_ >> 1) & 3)) * 8); } \
    _Pragma("unroll") for (int n_ = 0; n_ < 4; ++n_) { \
        const int rl_ = wn * 64 + n_ * 16 + l15 + (K) - 1; \
        const unsigned short* bp_ = xa + rl_ * 32 + (lhi ^ ((rl_ >> 1) & 3)) * 8; \
        if ((K) == 0 && n_ == 0 && rl_ < 0)   bp_ = halo + c0 + lhi * 8; \
        if ((K) == 2 && n_ == 3 && rl_ > 255) bp_ = halo + 512 + c0 + lhi * 8; \
        bv[n_] = *(const bf16x8*)bp_; } \
    __VA_ARGS__; \
    asm volatile("s_waitcnt lgkmcnt(0)" ::: "memory"); \
    __builtin_amdgcn_sched_barrier(0); \
    __builtin_amdgcn_s_setprio(1); \
    _Pragma("unroll") for (int n_ = 0; n_ < 4; ++n_) \
        _Pragma("unroll") for (int m_ = 0; m_ < 8; ++m_) \
            acc[m_][n_] = __builtin_amdgcn_mfma_f32_16x16x32_bf16(af[m_], bv[n_], acc[m_][n_], 0, 0, 0); \
    __builtin_amdgcn_s_setprio(0); }

__global__ __launch_bounds__(512, 1)
void k_conv(const unsigned short* __restrict__ kt,
            const unsigned short* __restrict__ xt,
            const float* __restrict__ demod,
            const float* __restrict__ kb,
            const float* __restrict__ zbuf,
            float* __restrict__ y) {
    const int t  = threadIdx.x;
    const int w0 = blockIdx.x * BN;
    const int f0 = blockIdx.y * BM;
    const int b  = blockIdx.z;

    const int wave = t >> 6;
    const int lane = t & 63;
    const int wm   = wave >> 2;
    const int wn   = wave & 3;
    const int l15  = lane & 15;
    const int lhi  = lane >> 4;

    unsigned short* halo = (unsigned short*)(smem + 2 * BUFB); // [2][512] c-natural

    f32x4 acc[8][4];
    #pragma unroll
    for (int m = 0; m < 8; ++m)
        #pragma unroll
        for (int n = 0; n < 4; ++n)
            #pragma unroll
            for (int r = 0; r < 4; ++r)
                acc[m][n][r] = 0.f;

    // prologue: halo (w0-1, w0+BN across all 512 c), then tile0 in group order
    if (t < 128) {
        const int h  = t >> 6;
        const int wg = h ? (w0 + BN) : (w0 - 1);
        const unsigned short* src = ((unsigned)wg < (unsigned)Wn)
            ? &xt[((size_t)b * Wn + wg) * Cn + (t & 63) * 8]
            : (const unsigned short*)zbuf;
        gload_lds16(src, halo + (size_t)t * 8);
    }
    ISSUE_XT(smem, 0);
    ISSUE_PLANE(smem, 0, 0);
    ISSUE_PLANE(smem, 0, 1);
    ISSUE_PLANE(smem, 0, 2);

    int cur = 0;
    for (int cc = 0; cc < Cn / BK; ++cc) {
        const unsigned short* ka = (const unsigned short*)(smem + cur * BUFB);
        const unsigned short* xa = ka + 3 * BM * BK;
        char* nbuf = smem + (cur ^ 1) * BUFB;
        const int c0 = cc * BK;
        const int c1 = c0 + BK;
        const bool pf = cc < Cn / BK - 1;
        // steady-state outstanding at each vmcnt: p0 waits past plane1+plane2 (4);
        // p1/p2 wait past 6 newer (planes behind + p0's 4 / p0+p1's 6)
        PHASE(0, 4, if (pf) { ISSUE_XT(nbuf, c1); ISSUE_PLANE(nbuf, c1, 0); });
        PHASE(1, 6, if (pf) { ISSUE_PLANE(nbuf, c1, 1); });
        PHASE(2, 6, if (pf) { ISSUE_PLANE(nbuf, c1, 2); });
        cur ^= 1;
    }

    // epilogue: demod * acc + kb, leaky_relu(0.2)
    #pragma unroll
    for (int m = 0; m < 8; ++m) {
        const int fb = f0 + wm * 128 + m * 16 + lhi * 4;
        const float4 dmv = *(const float4*)&demod[b * Fn + fb];
        const float4 kbv = *(const float4*)&kb[fb];
        const float dmf[4] = {dmv.x, dmv.y, dmv.z, dmv.w};
        const float kbf[4] = {kbv.x, kbv.y, kbv.z, kbv.w};
        #pragma unroll
        for (int n = 0; n < 4; ++n) {
            const int w = w0 + wn * 64 + n * 16 + l15;
            #pragma unroll
            for (int r = 0; r < 4; ++r) {
                float v = fmaf(acc[m][n][r], dmf[r], kbf[r]);
                v = (v >= 0.f) ? v : 0.2f * v;
                y[((size_t)(b * Fn + fb + r)) * Wn + w] = v;
            }
        }
    }
}

extern "C" void kernel_launch(void* const* d_in, const int* in_sizes, int n_in,
                              void* d_out, int out_size, void* d_ws, size_t ws_size,
                              hipStream_t stream) {
    const float* latent  = (const float*)d_in[0];
    const float* content = (const float*)d_in[1];
    const float* aw      = (const float*)d_in[2];
    const float* ab      = (const float*)d_in[3];
    const float* kw      = (const float*)d_in[4];
    const float* kb      = (const float*)d_in[5];
    float* y = (float*)d_out;

    char* ws = (char*)d_ws;
    float*          affine = (float*)(ws);                        // 32 KB
    float*          demod  = (float*)(ws + 32768);                // 32 KB
    float*          zbuf   = (float*)(ws + 65536);                // 64 B (zeroed)
    float*          Q      = (float*)(ws + 131072);               // 1 MB (aliases kt; consumed before k_tk)
    unsigned short* kt     = (unsigned short*)(ws + 131072);      // 1.5 MB
    unsigned short* xt     = (unsigned short*)(ws + 2u * 1024u * 1024u); // 64 MB
    if (ws_size < 2u * 1024u * 1024u + (size_t)Bn * Wn * Cn * 2u) return;

    hipFuncSetAttribute((const void*)k_conv,
                        hipFuncAttributeMaxDynamicSharedMemorySize, SMEMB);

    k_affine<<<dim3(Cn / 64, Bn),           256, 0, stream>>>(latent, aw, ab, affine, zbuf);
    k_qsum  <<<dim3(Cn * Fn / 1024),        256, 0, stream>>>(kw, Q);
    k_demod2<<<dim3(Fn / 64, Bn),           256, 0, stream>>>(Q, affine, demod);
    k_tk    <<<dim3(Cn / 32, Fn / 64, 3),   256, 0, stream>>>(kw, kt);
    k_tx    <<<dim3(Wn / 64, Cn / 64, Bn),  256, 0, stream>>>(content, affine, xt);
    k_conv  <<<dim3(Wn / BN, Fn / BM, Bn),  512, SMEMB, stream>>>(kt, xt, demod, kb, zbuf, y);
}